// Round 6
// baseline (1477.984 us; speedup 1.0000x reference)
//
#include <hip/hip_runtime.h>
#include <hip/hip_bf16.h>

// Problem constants
#define B_ROWS 16384
#define XC     10242      // 1 rate + 25 genre + 2186 director + 8030 actor
#define NGENRE 25
#define NDIR   2186
#define NACT   8030
#define EMB    32
#define KT_TOTAL 321      // ceil(10242/32) k-tiles of 32
#define OUTC   128

typedef __attribute__((ext_vector_type(8))) short bf16x8;
typedef __attribute__((ext_vector_type(4), aligned(4))) float f32x4a;   // 16B ld @4B align
typedef __attribute__((ext_vector_type(4))) float f32x4;
typedef __attribute__((ext_vector_type(8))) unsigned short u16x8;

// ---------------------------------------------------------------------------
// Fused kernel. 256 blocks x 256 threads; block = 64 rows (4 waves x 16 rows).
// Per k-tile (32 k): stage x (int32 0/1 -> bf16) in LDS, MFMA against B-frags
// built from global fp32 W (block-diagonal: active segment's 2 tiles + 1
// indicator tile). Counts via indicator MFMA; epilogue fused (divide,
// max-norm rate gather) with FP32 stores (reference output dtype = float32).
// A-frag: lane holds A[m=lane&15][k=(lane>>4)*8+j]
// B-frag: lane holds B[k=(lane>>4)*8+j][n=lane&15] = 8 contiguous W-row elems
// C/D:    row=(lane>>4)*4+j, col=lane&15
// Compute path proven: R3 (MFMA) == R5 (scalar) bit-identical outputs.
// ---------------------------------------------------------------------------
__global__ __launch_bounds__(256) void fused_k(const int* __restrict__ x,
                                               const float* __restrict__ rate,
                                               const float* __restrict__ wg,
                                               const float* __restrict__ wd,
                                               const float* __restrict__ wa,
                                               float* __restrict__ out) {
  __shared__ unsigned short ldsA[64 * 40];   // 64 rows x 32 bf16, stride 40

  const int t    = threadIdx.x;
  const int rb   = blockIdx.x;          // 0..255
  const int srow = t >> 2;              // staging row 0..63
  const int kg   = (t & 3) * 8;         // staging k offset
  const int* xrow = x + (size_t)(rb * 64 + srow) * XC;

  const int lane = t & 63;
  const int w    = t >> 6;
  const int lo   = lane & 15, hi = lane >> 4;

  f32x4 accG0 = {0.f,0.f,0.f,0.f}, accG1 = {0.f,0.f,0.f,0.f};
  f32x4 accD0 = {0.f,0.f,0.f,0.f}, accD1 = {0.f,0.f,0.f,0.f};
  f32x4 accA0 = {0.f,0.f,0.f,0.f}, accA1 = {0.f,0.f,0.f,0.f};
  f32x4 accI  = {0.f,0.f,0.f,0.f};

  auto load_x8 = [&](int kt, int* dst) {
    int k0 = kt * 32 + kg;
    if (k0 + 7 < XC) {                  // two 16B loads
      int4 a = *reinterpret_cast<const int4*>(xrow + k0);
      int4 b = *reinterpret_cast<const int4*>(xrow + k0 + 4);
      dst[0]=a.x; dst[1]=a.y; dst[2]=a.z; dst[3]=a.w;
      dst[4]=b.x; dst[5]=b.y; dst[6]=b.z; dst[7]=b.w;
    } else {
#pragma unroll
      for (int i = 0; i < 8; ++i) dst[i] = (k0 + i < XC) ? xrow[k0 + i] : 0;
    }
  };

  auto bfbits = [](float f) -> unsigned short {
    __hip_bfloat16 h = __float2bfloat16(f);
    return *reinterpret_cast<unsigned short*>(&h);
  };

  auto wval = [&](const float* base, int elem, bool inb) -> unsigned short {
    return inb ? bfbits(base[elem]) : (unsigned short)0;
  };

  auto fragv = [&](const float* base, int elem) -> bf16x8 {
    f32x4a a = *reinterpret_cast<const f32x4a*>(base + elem);
    f32x4a c = *reinterpret_cast<const f32x4a*>(base + elem + 4);
    union { unsigned short u[8]; bf16x8 v; } cv;
#pragma unroll
    for (int j = 0; j < 4; ++j) {
      cv.u[j]     = bfbits(a[j]);
      cv.u[j + 4] = bfbits(c[j]);
    }
    return cv.v;
  };

  auto pack8 = [](const unsigned short* s) -> bf16x8 {
    union { unsigned short u[8]; bf16x8 v; } cv;
#pragma unroll
    for (int i = 0; i < 8; ++i) cv.u[i] = s[i];
    return cv.v;
  };

  int xv[2][8];
  load_x8(0, xv[0]);
  load_x8(1, xv[1]);

  for (int kt = 0; kt < KT_TOTAL; ++kt) {
    int* cx = xv[kt & 1];
    unsigned short cur[8];
#pragma unroll
    for (int i = 0; i < 8; ++i)
      cur[i] = cx[i] ? (unsigned short)0x3F80 : (unsigned short)0;
    if (kt + 2 < KT_TOTAL) load_x8(kt + 2, xv[kt & 1]);   // depth-2 prefetch

    __syncthreads();
    *reinterpret_cast<u16x8*>(&ldsA[srow * 40 + kg]) =
        *reinterpret_cast<const u16x8*>(cur);
    __syncthreads();

    bf16x8 afrag = *reinterpret_cast<const bf16x8*>(&ldsA[(w * 16 + lo) * 40 + hi * 8]);
    const int kb = kt * 32 + hi * 8;

    { // indicator tile: col0 genre count, col1 director, col2 actor
      unsigned short iv[8];
#pragma unroll
      for (int j = 0; j < 8; ++j) {
        int k = kb + j;
        bool on = (lo == 0) ? (k >= 1 && k < 26)
                : (lo == 1) ? (k >= 26 && k < 2212)
                : (lo == 2) ? (k >= 2212 && k < XC)
                : false;
        iv[j] = on ? (unsigned short)0x3F80 : (unsigned short)0;
      }
      accI = __builtin_amdgcn_mfma_f32_16x16x32_bf16(afrag, pack8(iv), accI, 0, 0, 0);
    }

    if (kt == 0) {              // genre (k 1..25) + director head (26..31)
      unsigned short g0[8], g1[8], d0[8], d1[8];
#pragma unroll
      for (int j = 0; j < 8; ++j) {
        int k = kb + j;
        bool ing = (k >= 1 && k < 26);
        bool ind = (k >= 26);
        g0[j] = wval(wg, lo * NGENRE + (k - 1), ing);
        g1[j] = wval(wg, (16 + lo) * NGENRE + (k - 1), ing);
        d0[j] = wval(wd, lo * NDIR + (k - 26), ind);
        d1[j] = wval(wd, (16 + lo) * NDIR + (k - 26), ind);
      }
      accG0 = __builtin_amdgcn_mfma_f32_16x16x32_bf16(afrag, pack8(g0), accG0, 0, 0, 0);
      accG1 = __builtin_amdgcn_mfma_f32_16x16x32_bf16(afrag, pack8(g1), accG1, 0, 0, 0);
      accD0 = __builtin_amdgcn_mfma_f32_16x16x32_bf16(afrag, pack8(d0), accD0, 0, 0, 0);
      accD1 = __builtin_amdgcn_mfma_f32_16x16x32_bf16(afrag, pack8(d1), accD1, 0, 0, 0);
    } else if (kt < 69) {       // interior director
      int e0 = lo * NDIR + kb - 26, e1 = (16 + lo) * NDIR + kb - 26;
      bf16x8 b0 = fragv(wd, e0), b1 = fragv(wd, e1);
      accD0 = __builtin_amdgcn_mfma_f32_16x16x32_bf16(afrag, b0, accD0, 0, 0, 0);
      accD1 = __builtin_amdgcn_mfma_f32_16x16x32_bf16(afrag, b1, accD1, 0, 0, 0);
    } else if (kt == 69) {      // director tail + actor head
      unsigned short d0[8], d1[8], a0[8], a1[8];
#pragma unroll
      for (int j = 0; j < 8; ++j) {
        int k = kb + j;
        bool ind = (k < 2212);
        d0[j] = wval(wd, lo * NDIR + (k - 26), ind);
        d1[j] = wval(wd, (16 + lo) * NDIR + (k - 26), ind);
        a0[j] = wval(wa, lo * NACT + (k - 2212), !ind);
        a1[j] = wval(wa, (16 + lo) * NACT + (k - 2212), !ind);
      }
      accD0 = __builtin_amdgcn_mfma_f32_16x16x32_bf16(afrag, pack8(d0), accD0, 0, 0, 0);
      accD1 = __builtin_amdgcn_mfma_f32_16x16x32_bf16(afrag, pack8(d1), accD1, 0, 0, 0);
      accA0 = __builtin_amdgcn_mfma_f32_16x16x32_bf16(afrag, pack8(a0), accA0, 0, 0, 0);
      accA1 = __builtin_amdgcn_mfma_f32_16x16x32_bf16(afrag, pack8(a1), accA1, 0, 0, 0);
    } else if (kt < 320) {      // interior actor
      int e0 = lo * NACT + kb - 2212, e1 = (16 + lo) * NACT + kb - 2212;
      bf16x8 b0 = fragv(wa, e0), b1 = fragv(wa, e1);
      accA0 = __builtin_amdgcn_mfma_f32_16x16x32_bf16(afrag, b0, accA0, 0, 0, 0);
      accA1 = __builtin_amdgcn_mfma_f32_16x16x32_bf16(afrag, b1, accA1, 0, 0, 0);
    } else {                    // actor tail (k 10240..10241)
      unsigned short a0[8], a1[8];
#pragma unroll
      for (int j = 0; j < 8; ++j) {
        int k = kb + j;
        bool in = (k < XC);
        a0[j] = wval(wa, lo * NACT + (k - 2212), in);
        a1[j] = wval(wa, (16 + lo) * NACT + (k - 2212), in);
      }
      accA0 = __builtin_amdgcn_mfma_f32_16x16x32_bf16(afrag, pack8(a0), accA0, 0, 0, 0);
      accA1 = __builtin_amdgcn_mfma_f32_16x16x32_bf16(afrag, pack8(a1), accA1, 0, 0, 0);
    }
  }

  // ---- fused epilogue (FP32 output) ----
  float gc[4], dc[4], ac[4];
#pragma unroll
  for (int j = 0; j < 4; ++j) {
    gc[j] = __shfl(accI[j], (lane & 48));
    dc[j] = __shfl(accI[j], (lane & 48) | 1);
    ac[j] = __shfl(accI[j], (lane & 48) | 2);
  }

  const int rbase = rb * 64 + w * 16 + hi * 4;
#pragma unroll
  for (int j = 0; j < 4; ++j) {
    size_t ro = (size_t)(rbase + j) * OUTC;
    out[ro +  32 + lo] = accG0[j] / gc[j];
    out[ro +  48 + lo] = accG1[j] / gc[j];
    out[ro +  64 + lo] = accD0[j] / dc[j];
    out[ro +  80 + lo] = accD1[j] / dc[j];
    out[ro +  96 + lo] = accA0[j] / ac[j];
    out[ro + 112 + lo] = accA1[j] / ac[j];
  }

  // rate embedding with max-norm (cols 0..31), pure fp32
#pragma unroll
  for (int j = 0; j < 4; ++j) {
    int row = rbase + j;
    int idx = x[(size_t)row * XC];
    float v0 = rate[idx * EMB + 2 * lo];
    float v1 = rate[idx * EMB + 2 * lo + 1];
    float s2 = v0 * v0 + v1 * v1;
    s2 += __shfl_xor(s2, 1);
    s2 += __shfl_xor(s2, 2);
    s2 += __shfl_xor(s2, 4);
    s2 += __shfl_xor(s2, 8);
    float norm  = sqrtf(s2);
    float scale = (norm > 1.0f) ? (1.0f / (norm + 1e-7f)) : 1.0f;
    float2 pk = make_float2(v0 * scale, v1 * scale);
    reinterpret_cast<float2*>(out)[(size_t)row * 64 + lo] = pk;
  }
}

// ---------------------------------------------------------------------------
extern "C" void kernel_launch(void* const* d_in, const int* in_sizes, int n_in,
                              void* d_out, int out_size, void* d_ws, size_t ws_size,
                              hipStream_t stream) {
  (void)in_sizes; (void)n_in; (void)out_size; (void)d_ws; (void)ws_size;
  const int*   x    = (const int*)d_in[0];
  const float* rate = (const float*)d_in[1];
  const float* wg   = (const float*)d_in[2];
  const float* wd   = (const float*)d_in[3];
  const float* wa   = (const float*)d_in[4];
  float* out = (float*)d_out;   // reference output dtype = float32

  fused_k<<<256, 256, 0, stream>>>(x, rate, wg, wd, wa, out);
}

// Round 7
// 1053.043 us; speedup vs baseline: 1.4035x; 1.4035x over previous
//
#include <hip/hip_runtime.h>
#include <hip/hip_bf16.h>

// Problem constants
#define B_ROWS 16384
#define XC     10242      // 1 rate + 25 genre + 2186 director + 8030 actor
#define NGENRE 25
#define NDIR   2186
#define NACT   8030
#define EMB    32
#define KT_TOTAL 321      // ceil(10242/32) k-tiles of 32
#define OUTC   128
#define NCOLS  112        // slab cols: 96 emb + 3 counts + pad
#define PART_STRIDE ((size_t)B_ROWS * NCOLS)

typedef __attribute__((ext_vector_type(8))) short bf16x8;
typedef __attribute__((ext_vector_type(4), aligned(4))) float f32x4a;
typedef __attribute__((ext_vector_type(4))) float f32x4;
typedef __attribute__((ext_vector_type(8))) unsigned short u16x8;

// ===========================================================================
// Shared compute core (proven in R6): one block = 64 rows x k-range
// [ktA,ktB). Accumulates 6 weight C-frags + 1 indicator C-frag.
// A-frag: lane holds A[m=lane&15][k=(lane>>4)*8+j]
// B-frag: lane holds B[k=(lane>>4)*8+j][n=lane&15] = 8 contiguous W-row elems
// C/D:    row=(lane>>4)*4+j, col=lane&15
// ===========================================================================
__device__ __forceinline__ void compute_core(
    const int* __restrict__ xrow, int t, int ktA, int ktB,
    const float* __restrict__ wg, const float* __restrict__ wd,
    const float* __restrict__ wa, unsigned short* __restrict__ ldsA,
    f32x4& accG0, f32x4& accG1, f32x4& accD0, f32x4& accD1,
    f32x4& accA0, f32x4& accA1, f32x4& accI) {
  const int srow = t >> 2;
  const int kg   = (t & 3) * 8;
  const int lane = t & 63;
  const int w    = t >> 6;
  const int lo   = lane & 15, hi = lane >> 4;

  auto load_x8 = [&](int kt, int* dst) {
    int k0 = kt * 32 + kg;
    if (k0 + 7 < XC) {
      int4 a = *reinterpret_cast<const int4*>(xrow + k0);
      int4 b = *reinterpret_cast<const int4*>(xrow + k0 + 4);
      dst[0]=a.x; dst[1]=a.y; dst[2]=a.z; dst[3]=a.w;
      dst[4]=b.x; dst[5]=b.y; dst[6]=b.z; dst[7]=b.w;
    } else {
#pragma unroll
      for (int i = 0; i < 8; ++i) dst[i] = (k0 + i < XC) ? xrow[k0 + i] : 0;
    }
  };
  auto bfbits = [](float f) -> unsigned short {
    __hip_bfloat16 h = __float2bfloat16(f);
    return *reinterpret_cast<unsigned short*>(&h);
  };
  auto wval = [&](const float* base, int elem, bool inb) -> unsigned short {
    return inb ? bfbits(base[elem]) : (unsigned short)0;
  };
  auto fragv = [&](const float* base, int elem) -> bf16x8 {
    f32x4a a = *reinterpret_cast<const f32x4a*>(base + elem);
    f32x4a c = *reinterpret_cast<const f32x4a*>(base + elem + 4);
    union { unsigned short u[8]; bf16x8 v; } cv;
#pragma unroll
    for (int j = 0; j < 4; ++j) { cv.u[j] = bfbits(a[j]); cv.u[j+4] = bfbits(c[j]); }
    return cv.v;
  };
  auto pack8 = [](const unsigned short* s) -> bf16x8 {
    union { unsigned short u[8]; bf16x8 v; } cv;
#pragma unroll
    for (int i = 0; i < 8; ++i) cv.u[i] = s[i];
    return cv.v;
  };

  int xv[2][8];
  load_x8(ktA, xv[0]);
  if (ktA + 1 < ktB) load_x8(ktA + 1, xv[1]);

  for (int kt = ktA; kt < ktB; ++kt) {
    int* cx = xv[kt & 1];
    unsigned short cur[8];
#pragma unroll
    for (int i = 0; i < 8; ++i)
      cur[i] = cx[i] ? (unsigned short)0x3F80 : (unsigned short)0;
    if (kt + 2 < ktB) load_x8(kt + 2, xv[kt & 1]);

    __syncthreads();
    *reinterpret_cast<u16x8*>(&ldsA[srow * 40 + kg]) =
        *reinterpret_cast<const u16x8*>(cur);
    __syncthreads();

    bf16x8 afrag = *reinterpret_cast<const bf16x8*>(&ldsA[(w * 16 + lo) * 40 + hi * 8]);
    const int kb = kt * 32 + hi * 8;

    { // indicator tile: col0 genre count, col1 director, col2 actor
      unsigned short iv[8];
#pragma unroll
      for (int j = 0; j < 8; ++j) {
        int k = kb + j;
        bool on = (lo == 0) ? (k >= 1 && k < 26)
                : (lo == 1) ? (k >= 26 && k < 2212)
                : (lo == 2) ? (k >= 2212 && k < XC)
                : false;
        iv[j] = on ? (unsigned short)0x3F80 : (unsigned short)0;
      }
      accI = __builtin_amdgcn_mfma_f32_16x16x32_bf16(afrag, pack8(iv), accI, 0, 0, 0);
    }

    if (kt == 0) {
      unsigned short g0[8], g1[8], d0[8], d1[8];
#pragma unroll
      for (int j = 0; j < 8; ++j) {
        int k = kb + j;
        bool ing = (k >= 1 && k < 26);
        bool ind = (k >= 26);
        g0[j] = wval(wg, lo * NGENRE + (k - 1), ing);
        g1[j] = wval(wg, (16 + lo) * NGENRE + (k - 1), ing);
        d0[j] = wval(wd, lo * NDIR + (k - 26), ind);
        d1[j] = wval(wd, (16 + lo) * NDIR + (k - 26), ind);
      }
      accG0 = __builtin_amdgcn_mfma_f32_16x16x32_bf16(afrag, pack8(g0), accG0, 0, 0, 0);
      accG1 = __builtin_amdgcn_mfma_f32_16x16x32_bf16(afrag, pack8(g1), accG1, 0, 0, 0);
      accD0 = __builtin_amdgcn_mfma_f32_16x16x32_bf16(afrag, pack8(d0), accD0, 0, 0, 0);
      accD1 = __builtin_amdgcn_mfma_f32_16x16x32_bf16(afrag, pack8(d1), accD1, 0, 0, 0);
    } else if (kt < 69) {
      int e0 = lo * NDIR + kb - 26, e1 = (16 + lo) * NDIR + kb - 26;
      bf16x8 b0 = fragv(wd, e0), b1 = fragv(wd, e1);
      accD0 = __builtin_amdgcn_mfma_f32_16x16x32_bf16(afrag, b0, accD0, 0, 0, 0);
      accD1 = __builtin_amdgcn_mfma_f32_16x16x32_bf16(afrag, b1, accD1, 0, 0, 0);
    } else if (kt == 69) {
      unsigned short d0[8], d1[8], a0[8], a1[8];
#pragma unroll
      for (int j = 0; j < 8; ++j) {
        int k = kb + j;
        bool ind = (k < 2212);
        d0[j] = wval(wd, lo * NDIR + (k - 26), ind);
        d1[j] = wval(wd, (16 + lo) * NDIR + (k - 26), ind);
        a0[j] = wval(wa, lo * NACT + (k - 2212), !ind);
        a1[j] = wval(wa, (16 + lo) * NACT + (k - 2212), !ind);
      }
      accD0 = __builtin_amdgcn_mfma_f32_16x16x32_bf16(afrag, pack8(d0), accD0, 0, 0, 0);
      accD1 = __builtin_amdgcn_mfma_f32_16x16x32_bf16(afrag, pack8(d1), accD1, 0, 0, 0);
      accA0 = __builtin_amdgcn_mfma_f32_16x16x32_bf16(afrag, pack8(a0), accA0, 0, 0, 0);
      accA1 = __builtin_amdgcn_mfma_f32_16x16x32_bf16(afrag, pack8(a1), accA1, 0, 0, 0);
    } else if (kt < 320) {
      int e0 = lo * NACT + kb - 2212, e1 = (16 + lo) * NACT + kb - 2212;
      bf16x8 b0 = fragv(wa, e0), b1 = fragv(wa, e1);
      accA0 = __builtin_amdgcn_mfma_f32_16x16x32_bf16(afrag, b0, accA0, 0, 0, 0);
      accA1 = __builtin_amdgcn_mfma_f32_16x16x32_bf16(afrag, b1, accA1, 0, 0, 0);
    } else {
      unsigned short a0[8], a1[8];
#pragma unroll
      for (int j = 0; j < 8; ++j) {
        int k = kb + j;
        bool in = (k < XC);
        a0[j] = wval(wa, lo * NACT + (k - 2212), in);
        a1[j] = wval(wa, (16 + lo) * NACT + (k - 2212), in);
      }
      accA0 = __builtin_amdgcn_mfma_f32_16x16x32_bf16(afrag, pack8(a0), accA0, 0, 0, 0);
      accA1 = __builtin_amdgcn_mfma_f32_16x16x32_bf16(afrag, pack8(a1), accA1, 0, 0, 0);
    }
  }
}

// ===========================================================================
// K-split main: grid = KS*256 blocks; block (rb,ks) computes rows rb*64..+63
// over its k-range into private slab ks (plain stores, each cell written once).
// ===========================================================================
template<int KS>
__global__ __launch_bounds__(256) void main_mm(const int* __restrict__ x,
                                               const float* __restrict__ wg,
                                               const float* __restrict__ wd,
                                               const float* __restrict__ wa,
                                               float* __restrict__ part) {
  __shared__ unsigned short ldsA[64 * 40];
  constexpr int PER = (KT_TOTAL + KS - 1) / KS;

  const int t  = threadIdx.x;
  const int rb = blockIdx.x & 255;
  const int ks = blockIdx.x >> 8;
  const int ktA = ks * PER;
  const int ktB = (ktA + PER < KT_TOTAL) ? ktA + PER : KT_TOTAL;
  const int* xrow = x + (size_t)(rb * 64 + (t >> 2)) * XC;

  f32x4 accG0 = {0,0,0,0}, accG1 = {0,0,0,0};
  f32x4 accD0 = {0,0,0,0}, accD1 = {0,0,0,0};
  f32x4 accA0 = {0,0,0,0}, accA1 = {0,0,0,0};
  f32x4 accI  = {0,0,0,0};

  compute_core(xrow, t, ktA, ktB, wg, wd, wa, ldsA,
               accG0, accG1, accD0, accD1, accA0, accA1, accI);

  const int lane = t & 63;
  const int lo = lane & 15, hi = lane >> 4, w = t >> 6;
  float* slab = part + (size_t)ks * PART_STRIDE;
  const int rbase = rb * 64 + w * 16 + hi * 4;
#pragma unroll
  for (int j = 0; j < 4; ++j) {
    size_t ro = (size_t)(rbase + j) * NCOLS;
    slab[ro +  0 + lo] = accG0[j];
    slab[ro + 16 + lo] = accG1[j];
    slab[ro + 32 + lo] = accD0[j];
    slab[ro + 48 + lo] = accD1[j];
    slab[ro + 64 + lo] = accA0[j];
    slab[ro + 80 + lo] = accA1[j];
    if (lo < 3) slab[ro + 96 + lo] = accI[j];
  }
}

// ===========================================================================
// Reduce + epilogue: one row per 128-thread block. Sums KSPLIT slabs,
// divides by counts, max-norm rate gather, fp32 output.
// ===========================================================================
__global__ __launch_bounds__(128) void reduce_k(const int* __restrict__ x,
                                                const float* __restrict__ rate,
                                                const float* __restrict__ part,
                                                int ksplit,
                                                float* __restrict__ out) {
  __shared__ float cnt[3];
  const int r = blockIdx.x;
  const int c = threadIdx.x;

  if (c < 3) {
    float s = 0.f;
    for (int ks = 0; ks < ksplit; ++ks)
      s += part[(size_t)ks * PART_STRIDE + (size_t)r * NCOLS + 96 + c];
    cnt[c] = s;
  }
  __syncthreads();

  float res;
  if (c < EMB) {
    int idx = x[(size_t)r * XC];
    float v = rate[idx * EMB + c];
    float s2 = v * v;
    s2 += __shfl_xor(s2, 1, 32);
    s2 += __shfl_xor(s2, 2, 32);
    s2 += __shfl_xor(s2, 4, 32);
    s2 += __shfl_xor(s2, 8, 32);
    s2 += __shfl_xor(s2, 16, 32);
    float norm = sqrtf(s2);
    float scale = (norm > 1.0f) ? (1.0f / (norm + 1e-7f)) : 1.0f;
    res = v * scale;
  } else {
    int cc = c - EMB;                  // 0..95
    float val = 0.f;
    for (int ks = 0; ks < ksplit; ++ks)
      val += part[(size_t)ks * PART_STRIDE + (size_t)r * NCOLS + cc];
    res = val / cnt[cc >> 5];
  }
  out[(size_t)r * OUTC + c] = res;
}

// ===========================================================================
// Fallback direct kernel (R6, proven): used only if ws too small.
// ===========================================================================
__global__ __launch_bounds__(256) void fused_k(const int* __restrict__ x,
                                               const float* __restrict__ rate,
                                               const float* __restrict__ wg,
                                               const float* __restrict__ wd,
                                               const float* __restrict__ wa,
                                               float* __restrict__ out) {
  __shared__ unsigned short ldsA[64 * 40];
  const int t  = threadIdx.x;
  const int rb = blockIdx.x;
  const int* xrow = x + (size_t)(rb * 64 + (t >> 2)) * XC;

  f32x4 accG0 = {0,0,0,0}, accG1 = {0,0,0,0};
  f32x4 accD0 = {0,0,0,0}, accD1 = {0,0,0,0};
  f32x4 accA0 = {0,0,0,0}, accA1 = {0,0,0,0};
  f32x4 accI  = {0,0,0,0};

  compute_core(xrow, t, 0, KT_TOTAL, wg, wd, wa, ldsA,
               accG0, accG1, accD0, accD1, accA0, accA1, accI);

  const int lane = t & 63;
  const int lo = lane & 15, hi = lane >> 4, w = t >> 6;
  float gc[4], dc[4], ac[4];
#pragma unroll
  for (int j = 0; j < 4; ++j) {
    gc[j] = __shfl(accI[j], (lane & 48));
    dc[j] = __shfl(accI[j], (lane & 48) | 1);
    ac[j] = __shfl(accI[j], (lane & 48) | 2);
  }
  const int rbase = rb * 64 + w * 16 + hi * 4;
#pragma unroll
  for (int j = 0; j < 4; ++j) {
    size_t ro = (size_t)(rbase + j) * OUTC;
    out[ro +  32 + lo] = accG0[j] / gc[j];
    out[ro +  48 + lo] = accG1[j] / gc[j];
    out[ro +  64 + lo] = accD0[j] / dc[j];
    out[ro +  80 + lo] = accD1[j] / dc[j];
    out[ro +  96 + lo] = accA0[j] / ac[j];
    out[ro + 112 + lo] = accA1[j] / ac[j];
  }
#pragma unroll
  for (int j = 0; j < 4; ++j) {
    int row = rbase + j;
    int idx = x[(size_t)row * XC];
    float v0 = rate[idx * EMB + 2 * lo];
    float v1 = rate[idx * EMB + 2 * lo + 1];
    float s2 = v0 * v0 + v1 * v1;
    s2 += __shfl_xor(s2, 1);
    s2 += __shfl_xor(s2, 2);
    s2 += __shfl_xor(s2, 4);
    s2 += __shfl_xor(s2, 8);
    float norm = sqrtf(s2);
    float scale = (norm > 1.0f) ? (1.0f / (norm + 1e-7f)) : 1.0f;
    reinterpret_cast<float2*>(out)[(size_t)row * 64 + lo] =
        make_float2(v0 * scale, v1 * scale);
  }
}

// ---------------------------------------------------------------------------
extern "C" void kernel_launch(void* const* d_in, const int* in_sizes, int n_in,
                              void* d_out, int out_size, void* d_ws, size_t ws_size,
                              hipStream_t stream) {
  (void)in_sizes; (void)n_in; (void)out_size;
  const int*   x    = (const int*)d_in[0];
  const float* rate = (const float*)d_in[1];
  const float* wg   = (const float*)d_in[2];
  const float* wd   = (const float*)d_in[3];
  const float* wa   = (const float*)d_in[4];
  float* out  = (float*)d_out;
  float* part = (float*)d_ws;

  const size_t slab_bytes = PART_STRIDE * sizeof(float);   // 7.34 MB
  // Host-side choice on ws_size (host constant -> graph-capture safe).
  if (ws_size >= 8 * slab_bytes) {
    main_mm<8><<<8 * 256, 256, 0, stream>>>(x, wg, wd, wa, part);
    reduce_k<<<B_ROWS, 128, 0, stream>>>(x, rate, part, 8, out);
  } else if (ws_size >= 4 * slab_bytes) {
    main_mm<4><<<4 * 256, 256, 0, stream>>>(x, wg, wd, wa, part);
    reduce_k<<<B_ROWS, 128, 0, stream>>>(x, rate, part, 4, out);
  } else if (ws_size >= 2 * slab_bytes) {
    main_mm<2><<<2 * 256, 256, 0, stream>>>(x, wg, wd, wa, part);
    reduce_k<<<B_ROWS, 128, 0, stream>>>(x, rate, part, 2, out);
  } else {
    fused_k<<<256, 256, 0, stream>>>(x, rate, wg, wd, wa, out);
  }
}

// Round 8
// 955.999 us; speedup vs baseline: 1.5460x; 1.1015x over previous
//
#include <hip/hip_runtime.h>
#include <hip/hip_bf16.h>

// Problem constants
#define B_ROWS 16384
#define XC     10242      // 1 rate + 25 genre + 2186 director + 8030 actor
#define NGENRE 25
#define NDIR   2186
#define NACT   8030
#define EMB    32
#define KT_TOTAL 321      // ceil(10242/32) k-tiles of 32
#define OUTC   128
#define NCOLS  112        // slab cols: 96 emb + 3 counts + pad
#define PART_STRIDE ((size_t)B_ROWS * NCOLS)
#define WFRAG_BYTES ((size_t)KT_TOTAL * 4 * 64 * 16)   // 1.31 MB

typedef short bf16x8 __attribute__((ext_vector_type(8)));
typedef float f32x4  __attribute__((ext_vector_type(4)));
typedef int   i32x4a __attribute__((ext_vector_type(4), aligned(4)));

// ===========================================================================
// Prep: pre-convert the block-diagonal W into bf16 B-fragments, fragment-
// linear (one aligned 16B load per lane per frag in the main loop).
// B-frag: lane l holds B[k=kt*32+(l>>4)*8+j][n=l&15], j=0..7.
// 4 slots per kt: interior tiles use slots 0,1 (active segment halves);
// boundary tiles kt=0 (genre|director) and kt=69 (director|actor) use 0..3,
// pre-masked. Unused slots zeroed (never fed to MFMA, but keeps poison out).
// ===========================================================================
__global__ void prep_wfrag(const float* __restrict__ wg,
                           const float* __restrict__ wd,
                           const float* __restrict__ wa,
                           uint4* __restrict__ Wfrag) {
  const int kt = blockIdx.x;
  const int s  = threadIdx.x >> 6;       // slot 0..3
  const int l  = threadIdx.x & 63;
  const int n  = l & 15;
  const int k0 = kt * 32 + ((l >> 4) << 3);

  unsigned short v[8];
#pragma unroll
  for (int j = 0; j < 8; ++j) {
    const int k = k0 + j;
    float f = 0.f;
    if (kt == 0) {
      if (s < 2) { if (k >= 1 && k < 26) f = wg[(s * 16 + n) * NGENRE + (k - 1)]; }
      else       { if (k >= 26)          f = wd[((s - 2) * 16 + n) * NDIR + (k - 26)]; }
    } else if (kt < 69) {
      if (s < 2) f = wd[(s * 16 + n) * NDIR + (k - 26)];
    } else if (kt == 69) {
      if (s < 2) { if (k < 2212)  f = wd[(s * 16 + n) * NDIR + (k - 26)]; }
      else       { if (k >= 2212) f = wa[((s - 2) * 16 + n) * NACT + (k - 2212)]; }
    } else if (kt < 320) {
      if (s < 2) f = wa[(s * 16 + n) * NACT + (k - 2212)];
    } else {
      if (s < 2 && k < XC) f = wa[(s * 16 + n) * NACT + (k - 2212)];
    }
    __hip_bfloat16 h = __float2bfloat16(f);
    v[j] = *reinterpret_cast<unsigned short*>(&h);
  }
  union { unsigned short u[8]; uint4 q; } cv;
#pragma unroll
  for (int j = 0; j < 8; ++j) cv.u[j] = v[j];
  Wfrag[((size_t)kt * 4 + s) * 64 + l] = cv.q;
}

// ===========================================================================
// Main: barrier-free, LDS-free. Grid KS*256 x 256 threads; each wave owns 16
// rows (rb*64 + w*16 + lo) over k-range [ktA,ktB). A-frag = two dwordx4 of
// the lane's own row (lanes of equal lo cover 128B contiguous per row ->
// full line utilization, every x byte read once). B-frags from L2-resident
// pre-converted Wfrag. Counts via indicator MFMA (loop-invariant frags for
// interior tiles). Results to private fp32 slab (plain stores).
// A-frag: lane holds A[m=lane&15][k=(lane>>4)*8+j]
// C/D:    row=(lane>>4)*4+j, col=lane&15
// ===========================================================================
template<int KS>
__global__ __launch_bounds__(256) void main_mm(const int* __restrict__ x,
                                               const uint4* __restrict__ Wfrag,
                                               float* __restrict__ part) {
  constexpr int PER = (KT_TOTAL + KS - 1) / KS;
  const int t    = threadIdx.x;
  const int rb   = blockIdx.x & 255;
  const int ks   = blockIdx.x >> 8;
  const int ktA  = ks * PER;
  const int ktB  = (ktA + PER < KT_TOTAL) ? ktA + PER : KT_TOTAL;
  const int lane = t & 63;
  const int w    = t >> 6;
  const int lo   = lane & 15, hi = lane >> 4;
  const int* xrow = x + (size_t)(rb * 64 + w * 16 + lo) * XC;

  f32x4 accG0 = {0,0,0,0}, accG1 = {0,0,0,0};
  f32x4 accD0 = {0,0,0,0}, accD1 = {0,0,0,0};
  f32x4 accA0 = {0,0,0,0}, accA1 = {0,0,0,0};
  f32x4 accI  = {0,0,0,0};

  auto load_x8 = [&](int kt, int* dst) {
    int k0 = kt * 32 + hi * 8;
    if (k0 + 7 < XC) {
      i32x4a a = *reinterpret_cast<const i32x4a*>(xrow + k0);
      i32x4a b = *reinterpret_cast<const i32x4a*>(xrow + k0 + 4);
      dst[0]=a[0]; dst[1]=a[1]; dst[2]=a[2]; dst[3]=a[3];
      dst[4]=b[0]; dst[5]=b[1]; dst[6]=b[2]; dst[7]=b[3];
    } else {
#pragma unroll
      for (int j = 0; j < 8; ++j) dst[j] = (k0 + j < XC) ? xrow[k0 + j] : 0;
    }
  };
  auto bload = [&](int kt, int s) -> bf16x8 {
    union { uint4 q; bf16x8 v; } c;
    c.q = Wfrag[((size_t)kt * 4 + s) * 64 + lane];
    return c.v;
  };
  // loop-invariant indicator frags (interior tiles)
  auto mkconst = [&](bool on) -> bf16x8 {
    union { unsigned int w[4]; bf16x8 v; } c;
    unsigned int u = on ? 0x3F803F80u : 0u;
    c.w[0]=u; c.w[1]=u; c.w[2]=u; c.w[3]=u;
    return c.v;
  };
  const bf16x8 ivD = mkconst(lo == 1);
  const bf16x8 ivA = mkconst(lo == 2);

  int xv[2][8];
  load_x8(ktA, xv[0]);
  if (ktA + 1 < ktB) load_x8(ktA + 1, xv[1]);

  for (int kt = ktA; kt < ktB; ++kt) {
    int* cx = xv[kt & 1];
    union { unsigned int w[4]; bf16x8 v; } af;
#pragma unroll
    for (int i = 0; i < 4; ++i)
      af.w[i] = (cx[2*i] ? 0x3F80u : 0u) | (cx[2*i+1] ? 0x3F800000u : 0u);
    if (kt + 2 < ktB) load_x8(kt + 2, xv[kt & 1]);
    const bf16x8 a = af.v;
    const int kb = kt * 32 + hi * 8;

    if (kt == 0) {
      accG0 = __builtin_amdgcn_mfma_f32_16x16x32_bf16(a, bload(0,0), accG0, 0,0,0);
      accG1 = __builtin_amdgcn_mfma_f32_16x16x32_bf16(a, bload(0,1), accG1, 0,0,0);
      accD0 = __builtin_amdgcn_mfma_f32_16x16x32_bf16(a, bload(0,2), accD0, 0,0,0);
      accD1 = __builtin_amdgcn_mfma_f32_16x16x32_bf16(a, bload(0,3), accD1, 0,0,0);
      union { unsigned short u[8]; bf16x8 v; } iv;
#pragma unroll
      for (int j = 0; j < 8; ++j) {
        int k = kb + j;
        bool on = (lo == 0) ? (k >= 1 && k < 26) : (lo == 1) ? (k >= 26) : false;
        iv.u[j] = on ? (unsigned short)0x3F80 : (unsigned short)0;
      }
      accI = __builtin_amdgcn_mfma_f32_16x16x32_bf16(a, iv.v, accI, 0,0,0);
    } else if (kt < 69) {
      accD0 = __builtin_amdgcn_mfma_f32_16x16x32_bf16(a, bload(kt,0), accD0, 0,0,0);
      accD1 = __builtin_amdgcn_mfma_f32_16x16x32_bf16(a, bload(kt,1), accD1, 0,0,0);
      accI  = __builtin_amdgcn_mfma_f32_16x16x32_bf16(a, ivD, accI, 0,0,0);
    } else if (kt == 69) {
      accD0 = __builtin_amdgcn_mfma_f32_16x16x32_bf16(a, bload(69,0), accD0, 0,0,0);
      accD1 = __builtin_amdgcn_mfma_f32_16x16x32_bf16(a, bload(69,1), accD1, 0,0,0);
      accA0 = __builtin_amdgcn_mfma_f32_16x16x32_bf16(a, bload(69,2), accA0, 0,0,0);
      accA1 = __builtin_amdgcn_mfma_f32_16x16x32_bf16(a, bload(69,3), accA1, 0,0,0);
      union { unsigned short u[8]; bf16x8 v; } iv;
#pragma unroll
      for (int j = 0; j < 8; ++j) {
        int k = kb + j;
        bool on = (lo == 1) ? (k < 2212) : (lo == 2) ? (k >= 2212) : false;
        iv.u[j] = on ? (unsigned short)0x3F80 : (unsigned short)0;
      }
      accI = __builtin_amdgcn_mfma_f32_16x16x32_bf16(a, iv.v, accI, 0,0,0);
    } else if (kt < 320) {
      accA0 = __builtin_amdgcn_mfma_f32_16x16x32_bf16(a, bload(kt,0), accA0, 0,0,0);
      accA1 = __builtin_amdgcn_mfma_f32_16x16x32_bf16(a, bload(kt,1), accA1, 0,0,0);
      accI  = __builtin_amdgcn_mfma_f32_16x16x32_bf16(a, ivA, accI, 0,0,0);
    } else {
      accA0 = __builtin_amdgcn_mfma_f32_16x16x32_bf16(a, bload(320,0), accA0, 0,0,0);
      accA1 = __builtin_amdgcn_mfma_f32_16x16x32_bf16(a, bload(320,1), accA1, 0,0,0);
      union { unsigned short u[8]; bf16x8 v; } iv;
#pragma unroll
      for (int j = 0; j < 8; ++j) {
        int k = kb + j;
        iv.u[j] = (lo == 2 && k < XC) ? (unsigned short)0x3F80 : (unsigned short)0;
      }
      accI = __builtin_amdgcn_mfma_f32_16x16x32_bf16(a, iv.v, accI, 0,0,0);
    }
  }

  float* slab = part + (size_t)ks * PART_STRIDE;
  const int rbase = rb * 64 + w * 16 + hi * 4;
#pragma unroll
  for (int j = 0; j < 4; ++j) {
    size_t ro = (size_t)(rbase + j) * NCOLS;
    slab[ro +  0 + lo] = accG0[j];
    slab[ro + 16 + lo] = accG1[j];
    slab[ro + 32 + lo] = accD0[j];
    slab[ro + 48 + lo] = accD1[j];
    slab[ro + 64 + lo] = accA0[j];
    slab[ro + 80 + lo] = accA1[j];
    if (lo < 3) slab[ro + 96 + lo] = accI[j];
  }
}

// ===========================================================================
// Reduce + epilogue (R7-proven): one row per 128-thread block.
// ===========================================================================
__global__ __launch_bounds__(128) void reduce_k(const int* __restrict__ x,
                                                const float* __restrict__ rate,
                                                const float* __restrict__ part,
                                                int ksplit,
                                                float* __restrict__ out) {
  __shared__ float cnt[3];
  const int r = blockIdx.x;
  const int c = threadIdx.x;

  if (c < 3) {
    float s = 0.f;
    for (int ks = 0; ks < ksplit; ++ks)
      s += part[(size_t)ks * PART_STRIDE + (size_t)r * NCOLS + 96 + c];
    cnt[c] = s;
  }
  __syncthreads();

  float res;
  if (c < EMB) {
    int idx = x[(size_t)r * XC];
    float v = rate[idx * EMB + c];
    float s2 = v * v;
    s2 += __shfl_xor(s2, 1, 32);
    s2 += __shfl_xor(s2, 2, 32);
    s2 += __shfl_xor(s2, 4, 32);
    s2 += __shfl_xor(s2, 8, 32);
    s2 += __shfl_xor(s2, 16, 32);
    float norm = sqrtf(s2);
    float scale = (norm > 1.0f) ? (1.0f / (norm + 1e-7f)) : 1.0f;
    res = v * scale;
  } else {
    int cc = c - EMB;                  // 0..95
    float val = 0.f;
    for (int ks = 0; ks < ksplit; ++ks)
      val += part[(size_t)ks * PART_STRIDE + (size_t)r * NCOLS + cc];
    res = val / cnt[cc >> 5];
  }
  out[(size_t)r * OUTC + c] = res;
}

// ---------------------------------------------------------------------------
extern "C" void kernel_launch(void* const* d_in, const int* in_sizes, int n_in,
                              void* d_out, int out_size, void* d_ws, size_t ws_size,
                              hipStream_t stream) {
  (void)in_sizes; (void)n_in; (void)out_size;
  const int*   x    = (const int*)d_in[0];
  const float* rate = (const float*)d_in[1];
  const float* wg   = (const float*)d_in[2];
  const float* wd   = (const float*)d_in[3];
  const float* wa   = (const float*)d_in[4];
  float* out  = (float*)d_out;
  float* part = (float*)d_ws;

  const size_t slab_bytes = PART_STRIDE * sizeof(float);   // 7.34 MB
  // Host-side KS choice from ws_size (host constant -> graph-capture safe).
  int KS;
  if      (ws_size >= 8 * slab_bytes + WFRAG_BYTES) KS = 8;
  else if (ws_size >= 4 * slab_bytes + WFRAG_BYTES) KS = 4;
  else if (ws_size >= 2 * slab_bytes + WFRAG_BYTES) KS = 2;
  else                                              KS = 1;
  uint4* Wfrag = (uint4*)((char*)d_ws + (size_t)KS * slab_bytes);

  prep_wfrag<<<KT_TOTAL, 256, 0, stream>>>(wg, wd, wa, Wfrag);
  switch (KS) {
    case 8: main_mm<8><<<8 * 256, 256, 0, stream>>>(x, Wfrag, part); break;
    case 4: main_mm<4><<<4 * 256, 256, 0, stream>>>(x, Wfrag, part); break;
    case 2: main_mm<2><<<2 * 256, 256, 0, stream>>>(x, Wfrag, part); break;
    default: main_mm<1><<<1 * 256, 256, 0, stream>>>(x, Wfrag, part); break;
  }
  reduce_k<<<B_ROWS, 128, 0, stream>>>(x, rate, part, KS, out);
}

// Round 9
// 936.012 us; speedup vs baseline: 1.5790x; 1.0214x over previous
//
#include <hip/hip_runtime.h>
#include <hip/hip_bf16.h>

// Problem constants
#define B_ROWS 16384
#define XC     10242      // 1 rate + 25 genre + 2186 director + 8030 actor
#define NGENRE 25
#define NDIR   2186
#define NACT   8030
#define EMB    32
#define KT_TOTAL 321      // ceil(10242/32) k-tiles of 32
#define OUTC   128
#define NCOLS  112        // slab cols: 96 emb + 3 counts + pad
#define PART_STRIDE ((size_t)B_ROWS * NCOLS)
#define WFRAG_BYTES ((size_t)KT_TOTAL * 4 * 64 * 16)   // 1.31 MB

typedef short bf16x8 __attribute__((ext_vector_type(8)));
typedef float f32x4  __attribute__((ext_vector_type(4)));
typedef int   i32x4a __attribute__((ext_vector_type(4), aligned(4)));

// ===========================================================================
// Prep (proven R8): pre-convert block-diagonal W into bf16 B-fragments,
// fragment-linear. B-frag: lane l holds B[k=kt*32+(l>>4)*8+j][n=l&15].
// 4 slots/kt; boundary tiles (0: genre|director, 69: director|actor) use all
// 4 pre-masked; interior tiles use slots 0,1.
// ===========================================================================
__global__ void prep_wfrag(const float* __restrict__ wg,
                           const float* __restrict__ wd,
                           const float* __restrict__ wa,
                           uint4* __restrict__ Wfrag) {
  const int kt = blockIdx.x;
  const int s  = threadIdx.x >> 6;       // slot 0..3
  const int l  = threadIdx.x & 63;
  const int n  = l & 15;
  const int k0 = kt * 32 + ((l >> 4) << 3);

  unsigned short v[8];
#pragma unroll
  for (int j = 0; j < 8; ++j) {
    const int k = k0 + j;
    float f = 0.f;
    if (kt == 0) {
      if (s < 2) { if (k >= 1 && k < 26) f = wg[(s * 16 + n) * NGENRE + (k - 1)]; }
      else       { if (k >= 26)          f = wd[((s - 2) * 16 + n) * NDIR + (k - 26)]; }
    } else if (kt < 69) {
      if (s < 2) f = wd[(s * 16 + n) * NDIR + (k - 26)];
    } else if (kt == 69) {
      if (s < 2) { if (k < 2212)  f = wd[(s * 16 + n) * NDIR + (k - 26)]; }
      else       { if (k >= 2212) f = wa[((s - 2) * 16 + n) * NACT + (k - 2212)]; }
    } else if (kt < 320) {
      if (s < 2) f = wa[(s * 16 + n) * NACT + (k - 2212)];
    } else {
      if (s < 2 && k < XC) f = wa[(s * 16 + n) * NACT + (k - 2212)];
    }
    __hip_bfloat16 h = __float2bfloat16(f);
    v[j] = *reinterpret_cast<unsigned short*>(&h);
  }
  union { unsigned short u[8]; uint4 q; } cv;
#pragma unroll
  for (int j = 0; j < 8; ++j) cv.u[j] = v[j];
  Wfrag[((size_t)kt * 4 + s) * 64 + l] = cv.q;
}

// ===========================================================================
// Main: barrier-free, LDS-free, and now SCRATCH-FREE: the k-loop is manually
// unrolled by 2 with two explicit register buffers (xv0/xv1, all constant
// indices) instead of the R8 xv[kt&1] dynamic index that could spill the
// prefetch buffer to scratch. ktA forced even (PER rounded even) so the
// unroll phase is static. Packing: (cx0 + (cx1<<16)) * 0x3F80 -> exact
// packed bf16 pair for x in {0,1}, 2 VALU/pair.
// A-frag: lane holds A[m=lane&15][k=(lane>>4)*8+j]; C/D row=(lane>>4)*4+j,
// col=lane&15.
// ===========================================================================
template<int KS>
__global__ __launch_bounds__(256) void main_mm(const int* __restrict__ x,
                                               const uint4* __restrict__ Wfrag,
                                               float* __restrict__ part) {
  constexpr int PER = ((KT_TOTAL + KS - 1) / KS + 1) & ~1;   // even
  const int t    = threadIdx.x;
  const int rb   = blockIdx.x & 255;
  const int ks   = blockIdx.x >> 8;
  const int ktA  = ks * PER;                                  // even
  const int ktB  = (ktA + PER < KT_TOTAL) ? ktA + PER : KT_TOTAL;
  const int lane = t & 63;
  const int w    = t >> 6;
  const int lo   = lane & 15, hi = lane >> 4;
  const int* xrow = x + (size_t)(rb * 64 + w * 16 + lo) * XC;

  f32x4 accG0 = {0,0,0,0}, accG1 = {0,0,0,0};
  f32x4 accD0 = {0,0,0,0}, accD1 = {0,0,0,0};
  f32x4 accA0 = {0,0,0,0}, accA1 = {0,0,0,0};
  f32x4 accI  = {0,0,0,0};

  auto load_x8 = [&](int kt, int* dst) {
    int k0 = kt * 32 + hi * 8;
    if (kt < 320) {          // wave-uniform: k0+7 <= 319*32+31 = 10239 < XC
      i32x4a a = *reinterpret_cast<const i32x4a*>(xrow + k0);
      i32x4a b = *reinterpret_cast<const i32x4a*>(xrow + k0 + 4);
      dst[0]=a[0]; dst[1]=a[1]; dst[2]=a[2]; dst[3]=a[3];
      dst[4]=b[0]; dst[5]=b[1]; dst[6]=b[2]; dst[7]=b[3];
    } else {                 // tail tile: per-lane masked scalar loads
#pragma unroll
      for (int j = 0; j < 8; ++j) dst[j] = (k0 + j < XC) ? xrow[k0 + j] : 0;
    }
  };
  auto packa = [&](const int* cx) -> bf16x8 {
    union { unsigned int w4[4]; bf16x8 v; } af;
#pragma unroll
    for (int i = 0; i < 4; ++i)
      af.w4[i] = ((unsigned)cx[2*i] + ((unsigned)cx[2*i+1] << 16)) * 0x3F80u;
    return af.v;
  };
  auto bload = [&](int kt, int s) -> bf16x8 {
    union { uint4 q; bf16x8 v; } c;
    c.q = Wfrag[((size_t)kt * 4 + s) * 64 + lane];
    return c.v;
  };
  auto mkconst = [&](bool on) -> bf16x8 {
    union { unsigned int w4[4]; bf16x8 v; } c;
    unsigned int u = on ? 0x3F803F80u : 0u;
    c.w4[0]=u; c.w4[1]=u; c.w4[2]=u; c.w4[3]=u;
    return c.v;
  };
  const bf16x8 ivD = mkconst(lo == 1);
  const bf16x8 ivA = mkconst(lo == 2);

  auto do_mfma = [&](int kt, bf16x8 a) {
    const int kb = kt * 32 + hi * 8;
    if (kt == 0) {
      accG0 = __builtin_amdgcn_mfma_f32_16x16x32_bf16(a, bload(0,0), accG0, 0,0,0);
      accG1 = __builtin_amdgcn_mfma_f32_16x16x32_bf16(a, bload(0,1), accG1, 0,0,0);
      accD0 = __builtin_amdgcn_mfma_f32_16x16x32_bf16(a, bload(0,2), accD0, 0,0,0);
      accD1 = __builtin_amdgcn_mfma_f32_16x16x32_bf16(a, bload(0,3), accD1, 0,0,0);
      union { unsigned short u[8]; bf16x8 v; } iv;
#pragma unroll
      for (int j = 0; j < 8; ++j) {
        int k = kb + j;
        bool on = (lo == 0) ? (k >= 1 && k < 26) : (lo == 1) ? (k >= 26) : false;
        iv.u[j] = on ? (unsigned short)0x3F80 : (unsigned short)0;
      }
      accI = __builtin_amdgcn_mfma_f32_16x16x32_bf16(a, iv.v, accI, 0,0,0);
    } else if (kt < 69) {
      accD0 = __builtin_amdgcn_mfma_f32_16x16x32_bf16(a, bload(kt,0), accD0, 0,0,0);
      accD1 = __builtin_amdgcn_mfma_f32_16x16x32_bf16(a, bload(kt,1), accD1, 0,0,0);
      accI  = __builtin_amdgcn_mfma_f32_16x16x32_bf16(a, ivD, accI, 0,0,0);
    } else if (kt == 69) {
      accD0 = __builtin_amdgcn_mfma_f32_16x16x32_bf16(a, bload(69,0), accD0, 0,0,0);
      accD1 = __builtin_amdgcn_mfma_f32_16x16x32_bf16(a, bload(69,1), accD1, 0,0,0);
      accA0 = __builtin_amdgcn_mfma_f32_16x16x32_bf16(a, bload(69,2), accA0, 0,0,0);
      accA1 = __builtin_amdgcn_mfma_f32_16x16x32_bf16(a, bload(69,3), accA1, 0,0,0);
      union { unsigned short u[8]; bf16x8 v; } iv;
#pragma unroll
      for (int j = 0; j < 8; ++j) {
        int k = kb + j;
        bool on = (lo == 1) ? (k < 2212) : (lo == 2) ? (k >= 2212) : false;
        iv.u[j] = on ? (unsigned short)0x3F80 : (unsigned short)0;
      }
      accI = __builtin_amdgcn_mfma_f32_16x16x32_bf16(a, iv.v, accI, 0,0,0);
    } else if (kt < 320) {
      accA0 = __builtin_amdgcn_mfma_f32_16x16x32_bf16(a, bload(kt,0), accA0, 0,0,0);
      accA1 = __builtin_amdgcn_mfma_f32_16x16x32_bf16(a, bload(kt,1), accA1, 0,0,0);
      accI  = __builtin_amdgcn_mfma_f32_16x16x32_bf16(a, ivA, accI, 0,0,0);
    } else {
      accA0 = __builtin_amdgcn_mfma_f32_16x16x32_bf16(a, bload(320,0), accA0, 0,0,0);
      accA1 = __builtin_amdgcn_mfma_f32_16x16x32_bf16(a, bload(320,1), accA1, 0,0,0);
      union { unsigned short u[8]; bf16x8 v; } iv;
#pragma unroll
      for (int j = 0; j < 8; ++j) {
        int k = kb + j;
        iv.u[j] = (lo == 2 && k < XC) ? (unsigned short)0x3F80 : (unsigned short)0;
      }
      accI = __builtin_amdgcn_mfma_f32_16x16x32_bf16(a, iv.v, accI, 0,0,0);
    }
  };

  // Manually unrolled-by-2 k-loop: xv0/xv1 are pure register buffers
  // (constant indices only), depth-2 prefetch.
  if (ktA < ktB) {
    int xv0[8], xv1[8];
    load_x8(ktA, xv0);
    if (ktA + 1 < ktB) load_x8(ktA + 1, xv1);
    int kt = ktA;
    while (true) {
      { // even phase: consumes xv0
        bf16x8 a = packa(xv0);
        if (kt + 2 < ktB) load_x8(kt + 2, xv0);
        do_mfma(kt, a);
        ++kt;
        if (kt >= ktB) break;
      }
      { // odd phase: consumes xv1
        bf16x8 a = packa(xv1);
        if (kt + 2 < ktB) load_x8(kt + 2, xv1);
        do_mfma(kt, a);
        ++kt;
        if (kt >= ktB) break;
      }
    }
  }

  float* slab = part + (size_t)ks * PART_STRIDE;
  const int rbase = rb * 64 + w * 16 + hi * 4;
#pragma unroll
  for (int j = 0; j < 4; ++j) {
    size_t ro = (size_t)(rbase + j) * NCOLS;
    slab[ro +  0 + lo] = accG0[j];
    slab[ro + 16 + lo] = accG1[j];
    slab[ro + 32 + lo] = accD0[j];
    slab[ro + 48 + lo] = accD1[j];
    slab[ro + 64 + lo] = accA0[j];
    slab[ro + 80 + lo] = accA1[j];
    if (lo < 3) slab[ro + 96 + lo] = accI[j];
  }
}

// ===========================================================================
// Reduce + epilogue (proven): one row per 128-thread block.
// ===========================================================================
__global__ __launch_bounds__(128) void reduce_k(const int* __restrict__ x,
                                                const float* __restrict__ rate,
                                                const float* __restrict__ part,
                                                int ksplit,
                                                float* __restrict__ out) {
  __shared__ float cnt[3];
  const int r = blockIdx.x;
  const int c = threadIdx.x;

  if (c < 3) {
    float s = 0.f;
    for (int ks = 0; ks < ksplit; ++ks)
      s += part[(size_t)ks * PART_STRIDE + (size_t)r * NCOLS + 96 + c];
    cnt[c] = s;
  }
  __syncthreads();

  float res;
  if (c < EMB) {
    int idx = x[(size_t)r * XC];
    float v = rate[idx * EMB + c];
    float s2 = v * v;
    s2 += __shfl_xor(s2, 1, 32);
    s2 += __shfl_xor(s2, 2, 32);
    s2 += __shfl_xor(s2, 4, 32);
    s2 += __shfl_xor(s2, 8, 32);
    s2 += __shfl_xor(s2, 16, 32);
    float norm = sqrtf(s2);
    float scale = (norm > 1.0f) ? (1.0f / (norm + 1e-7f)) : 1.0f;
    res = v * scale;
  } else {
    int cc = c - EMB;                  // 0..95
    float val = 0.f;
    for (int ks = 0; ks < ksplit; ++ks)
      val += part[(size_t)ks * PART_STRIDE + (size_t)r * NCOLS + cc];
    res = val / cnt[cc >> 5];
  }
  out[(size_t)r * OUTC + c] = res;
}

// ---------------------------------------------------------------------------
extern "C" void kernel_launch(void* const* d_in, const int* in_sizes, int n_in,
                              void* d_out, int out_size, void* d_ws, size_t ws_size,
                              hipStream_t stream) {
  (void)in_sizes; (void)n_in; (void)out_size;
  const int*   x    = (const int*)d_in[0];
  const float* rate = (const float*)d_in[1];
  const float* wg   = (const float*)d_in[2];
  const float* wd   = (const float*)d_in[3];
  const float* wa   = (const float*)d_in[4];
  float* out  = (float*)d_out;
  float* part = (float*)d_ws;

  const size_t slab_bytes = PART_STRIDE * sizeof(float);   // 7.34 MB
  // Host-side KS choice from ws_size (host constant -> graph-capture safe).
  int KS;
  if      (ws_size >= 8 * slab_bytes + WFRAG_BYTES) KS = 8;
  else if (ws_size >= 4 * slab_bytes + WFRAG_BYTES) KS = 4;
  else if (ws_size >= 2 * slab_bytes + WFRAG_BYTES) KS = 2;
  else                                              KS = 1;
  uint4* Wfrag = (uint4*)((char*)d_ws + (size_t)KS * slab_bytes);

  prep_wfrag<<<KT_TOTAL, 256, 0, stream>>>(wg, wd, wa, Wfrag);
  switch (KS) {
    case 8: main_mm<8><<<8 * 256, 256, 0, stream>>>(x, Wfrag, part); break;
    case 4: main_mm<4><<<4 * 256, 256, 0, stream>>>(x, Wfrag, part); break;
    case 2: main_mm<2><<<2 * 256, 256, 0, stream>>>(x, Wfrag, part); break;
    default: main_mm<1><<<1 * 256, 256, 0, stream>>>(x, Wfrag, part); break;
  }
  reduce_k<<<B_ROWS, 128, 0, stream>>>(x, rate, part, KS, out);
}

// Round 10
// 923.422 us; speedup vs baseline: 1.6006x; 1.0136x over previous
//
#include <hip/hip_runtime.h>
#include <hip/hip_bf16.h>

// Problem constants
#define B_ROWS 16384
#define XC     10242      // 1 rate + 25 genre + 2186 director + 8030 actor
#define NGENRE 25
#define NDIR   2186
#define NACT   8030
#define EMB    32
#define KT_TOTAL 321      // ceil(10242/32) k-tiles of 32
#define OUTC   128
#define NCOLS  112        // slab cols: 96 emb + 3 counts + pad
#define PART_STRIDE ((size_t)B_ROWS * NCOLS)
#define WFRAG_BYTES ((size_t)KT_TOTAL * 4 * 64 * 16)   // 1.31 MB

typedef short bf16x8 __attribute__((ext_vector_type(8)));
typedef float f32x4  __attribute__((ext_vector_type(4)));
typedef int   i32x4a __attribute__((ext_vector_type(4), aligned(4)));

// ===========================================================================
// Prep (proven): pre-convert block-diagonal W into bf16 B-fragments,
// fragment-linear. B-frag: lane l holds B[k=kt*32+(l>>4)*8+j][n=l&15].
// 4 slots/kt; boundary tiles (0: genre|director, 69: director|actor) use all
// 4 pre-masked; interior tiles use slots 0,1.
// ===========================================================================
__global__ void prep_wfrag(const float* __restrict__ wg,
                           const float* __restrict__ wd,
                           const float* __restrict__ wa,
                           uint4* __restrict__ Wfrag) {
  const int kt = blockIdx.x;
  const int s  = threadIdx.x >> 6;       // slot 0..3
  const int l  = threadIdx.x & 63;
  const int n  = l & 15;
  const int k0 = kt * 32 + ((l >> 4) << 3);

  unsigned short v[8];
#pragma unroll
  for (int j = 0; j < 8; ++j) {
    const int k = k0 + j;
    float f = 0.f;
    if (kt == 0) {
      if (s < 2) { if (k >= 1 && k < 26) f = wg[(s * 16 + n) * NGENRE + (k - 1)]; }
      else       { if (k >= 26)          f = wd[((s - 2) * 16 + n) * NDIR + (k - 26)]; }
    } else if (kt < 69) {
      if (s < 2) f = wd[(s * 16 + n) * NDIR + (k - 26)];
    } else if (kt == 69) {
      if (s < 2) { if (k < 2212)  f = wd[(s * 16 + n) * NDIR + (k - 26)]; }
      else       { if (k >= 2212) f = wa[((s - 2) * 16 + n) * NACT + (k - 2212)]; }
    } else if (kt < 320) {
      if (s < 2) f = wa[(s * 16 + n) * NACT + (k - 2212)];
    } else {
      if (s < 2 && k < XC) f = wa[(s * 16 + n) * NACT + (k - 2212)];
    }
    __hip_bfloat16 h = __float2bfloat16(f);
    v[j] = *reinterpret_cast<unsigned short*>(&h);
  }
  union { unsigned short u[8]; uint4 q; } cv;
#pragma unroll
  for (int j = 0; j < 8; ++j) cv.u[j] = v[j];
  Wfrag[((size_t)kt * 4 + s) * 64 + l] = cv.q;
}

// ===========================================================================
// Main: barrier-free, LDS-free. NEW in R10: K-unroll x4 — per group of 4
// tiles, all 8 dwordx4 x-loads issue up front so each of the wave's 16 row
// streams receives a 512-B contiguous burst per DRAM visit (4x fewer row
// activations vs per-tile 128-B visits). Buffers xg0..xg3 are statically
// indexed (registers, no scratch). Consumption is tile-by-tile; compiler's
// fine-grained vmcnt overlaps tile-0 MFMAs with tiles 1-3 in flight.
// A-frag: lane holds A[m=lane&15][k=(lane>>4)*8+j]; C/D row=(lane>>4)*4+j,
// col=lane&15. Pack: (x0 + (x1<<16)) * 0x3F80 (exact for x in {0,1}).
// ===========================================================================
template<int KS>
__global__ __launch_bounds__(256) void main_mm(const int* __restrict__ x,
                                               const uint4* __restrict__ Wfrag,
                                               float* __restrict__ part) {
  constexpr int PER = (((KT_TOTAL + KS - 1) / KS) + 3) & ~3;   // multiple of 4
  const int t    = threadIdx.x;
  const int rb   = blockIdx.x & 255;
  const int ks   = blockIdx.x >> 8;
  const int ktA  = ks * PER;
  const int ktB  = (ktA + PER < KT_TOTAL) ? ktA + PER : KT_TOTAL;
  const int lane = t & 63;
  const int w    = t >> 6;
  const int lo   = lane & 15, hi = lane >> 4;
  const int* xrow = x + (size_t)(rb * 64 + w * 16 + lo) * XC;

  f32x4 accG0 = {0,0,0,0}, accG1 = {0,0,0,0};
  f32x4 accD0 = {0,0,0,0}, accD1 = {0,0,0,0};
  f32x4 accA0 = {0,0,0,0}, accA1 = {0,0,0,0};
  f32x4 accI  = {0,0,0,0};

  auto load_x8 = [&](int kt, int* dst) {
    int k0 = kt * 32 + hi * 8;
    if (kt < 320) {          // wave-uniform: k0+7 <= 10239 < XC
      i32x4a a = *reinterpret_cast<const i32x4a*>(xrow + k0);
      i32x4a b = *reinterpret_cast<const i32x4a*>(xrow + k0 + 4);
      dst[0]=a[0]; dst[1]=a[1]; dst[2]=a[2]; dst[3]=a[3];
      dst[4]=b[0]; dst[5]=b[1]; dst[6]=b[2]; dst[7]=b[3];
    } else {                 // tail tile: per-lane masked scalar loads
#pragma unroll
      for (int j = 0; j < 8; ++j) dst[j] = (k0 + j < XC) ? xrow[k0 + j] : 0;
    }
  };
  auto packa = [&](const int* cx) -> bf16x8 {
    union { unsigned int w4[4]; bf16x8 v; } af;
#pragma unroll
    for (int i = 0; i < 4; ++i)
      af.w4[i] = ((unsigned)cx[2*i] + ((unsigned)cx[2*i+1] << 16)) * 0x3F80u;
    return af.v;
  };
  auto bload = [&](int kt, int s) -> bf16x8 {
    union { uint4 q; bf16x8 v; } c;
    c.q = Wfrag[((size_t)kt * 4 + s) * 64 + lane];
    return c.v;
  };
  auto mkconst = [&](bool on) -> bf16x8 {
    union { unsigned int w4[4]; bf16x8 v; } c;
    unsigned int u = on ? 0x3F803F80u : 0u;
    c.w4[0]=u; c.w4[1]=u; c.w4[2]=u; c.w4[3]=u;
    return c.v;
  };
  const bf16x8 ivD = mkconst(lo == 1);
  const bf16x8 ivA = mkconst(lo == 2);

  auto do_mfma = [&](int kt, bf16x8 a) {
    const int kb = kt * 32 + hi * 8;
    if (kt == 0) {
      accG0 = __builtin_amdgcn_mfma_f32_16x16x32_bf16(a, bload(0,0), accG0, 0,0,0);
      accG1 = __builtin_amdgcn_mfma_f32_16x16x32_bf16(a, bload(0,1), accG1, 0,0,0);
      accD0 = __builtin_amdgcn_mfma_f32_16x16x32_bf16(a, bload(0,2), accD0, 0,0,0);
      accD1 = __builtin_amdgcn_mfma_f32_16x16x32_bf16(a, bload(0,3), accD1, 0,0,0);
      union { unsigned short u[8]; bf16x8 v; } iv;
#pragma unroll
      for (int j = 0; j < 8; ++j) {
        int k = kb + j;
        bool on = (lo == 0) ? (k >= 1 && k < 26) : (lo == 1) ? (k >= 26) : false;
        iv.u[j] = on ? (unsigned short)0x3F80 : (unsigned short)0;
      }
      accI = __builtin_amdgcn_mfma_f32_16x16x32_bf16(a, iv.v, accI, 0,0,0);
    } else if (kt < 69) {
      accD0 = __builtin_amdgcn_mfma_f32_16x16x32_bf16(a, bload(kt,0), accD0, 0,0,0);
      accD1 = __builtin_amdgcn_mfma_f32_16x16x32_bf16(a, bload(kt,1), accD1, 0,0,0);
      accI  = __builtin_amdgcn_mfma_f32_16x16x32_bf16(a, ivD, accI, 0,0,0);
    } else if (kt == 69) {
      accD0 = __builtin_amdgcn_mfma_f32_16x16x32_bf16(a, bload(69,0), accD0, 0,0,0);
      accD1 = __builtin_amdgcn_mfma_f32_16x16x32_bf16(a, bload(69,1), accD1, 0,0,0);
      accA0 = __builtin_amdgcn_mfma_f32_16x16x32_bf16(a, bload(69,2), accA0, 0,0,0);
      accA1 = __builtin_amdgcn_mfma_f32_16x16x32_bf16(a, bload(69,3), accA1, 0,0,0);
      union { unsigned short u[8]; bf16x8 v; } iv;
#pragma unroll
      for (int j = 0; j < 8; ++j) {
        int k = kb + j;
        bool on = (lo == 1) ? (k < 2212) : (lo == 2) ? (k >= 2212) : false;
        iv.u[j] = on ? (unsigned short)0x3F80 : (unsigned short)0;
      }
      accI = __builtin_amdgcn_mfma_f32_16x16x32_bf16(a, iv.v, accI, 0,0,0);
    } else if (kt < 320) {
      accA0 = __builtin_amdgcn_mfma_f32_16x16x32_bf16(a, bload(kt,0), accA0, 0,0,0);
      accA1 = __builtin_amdgcn_mfma_f32_16x16x32_bf16(a, bload(kt,1), accA1, 0,0,0);
      accI  = __builtin_amdgcn_mfma_f32_16x16x32_bf16(a, ivA, accI, 0,0,0);
    } else {
      accA0 = __builtin_amdgcn_mfma_f32_16x16x32_bf16(a, bload(320,0), accA0, 0,0,0);
      accA1 = __builtin_amdgcn_mfma_f32_16x16x32_bf16(a, bload(320,1), accA1, 0,0,0);
      union { unsigned short u[8]; bf16x8 v; } iv;
#pragma unroll
      for (int j = 0; j < 8; ++j) {
        int k = kb + j;
        iv.u[j] = (lo == 2 && k < XC) ? (unsigned short)0x3F80 : (unsigned short)0;
      }
      accI = __builtin_amdgcn_mfma_f32_16x16x32_bf16(a, iv.v, accI, 0,0,0);
    }
  };

  // Group-of-4 k-loop: issue the whole group's loads (512-B burst per row
  // stream), then consume tile-by-tile. All buffers statically indexed.
  int xg0[8], xg1[8], xg2[8], xg3[8];
  for (int g = ktA; g < ktB; g += 4) {
    load_x8(g, xg0);
    if (g + 1 < ktB) load_x8(g + 1, xg1);
    if (g + 2 < ktB) load_x8(g + 2, xg2);
    if (g + 3 < ktB) load_x8(g + 3, xg3);

    do_mfma(g, packa(xg0));
    if (g + 1 < ktB) do_mfma(g + 1, packa(xg1));
    if (g + 2 < ktB) do_mfma(g + 2, packa(xg2));
    if (g + 3 < ktB) do_mfma(g + 3, packa(xg3));
  }

  float* slab = part + (size_t)ks * PART_STRIDE;
  const int rbase = rb * 64 + w * 16 + hi * 4;
#pragma unroll
  for (int j = 0; j < 4; ++j) {
    size_t ro = (size_t)(rbase + j) * NCOLS;
    slab[ro +  0 + lo] = accG0[j];
    slab[ro + 16 + lo] = accG1[j];
    slab[ro + 32 + lo] = accD0[j];
    slab[ro + 48 + lo] = accD1[j];
    slab[ro + 64 + lo] = accA0[j];
    slab[ro + 80 + lo] = accA1[j];
    if (lo < 3) slab[ro + 96 + lo] = accI[j];
  }
}

// ===========================================================================
// Reduce + epilogue (proven): one row per 128-thread block.
// ===========================================================================
__global__ __launch_bounds__(128) void reduce_k(const int* __restrict__ x,
                                                const float* __restrict__ rate,
                                                const float* __restrict__ part,
                                                int ksplit,
                                                float* __restrict__ out) {
  __shared__ float cnt[3];
  const int r = blockIdx.x;
  const int c = threadIdx.x;

  if (c < 3) {
    float s = 0.f;
    for (int ks = 0; ks < ksplit; ++ks)
      s += part[(size_t)ks * PART_STRIDE + (size_t)r * NCOLS + 96 + c];
    cnt[c] = s;
  }
  __syncthreads();

  float res;
  if (c < EMB) {
    int idx = x[(size_t)r * XC];
    float v = rate[idx * EMB + c];
    float s2 = v * v;
    s2 += __shfl_xor(s2, 1, 32);
    s2 += __shfl_xor(s2, 2, 32);
    s2 += __shfl_xor(s2, 4, 32);
    s2 += __shfl_xor(s2, 8, 32);
    s2 += __shfl_xor(s2, 16, 32);
    float norm = sqrtf(s2);
    float scale = (norm > 1.0f) ? (1.0f / (norm + 1e-7f)) : 1.0f;
    res = v * scale;
  } else {
    int cc = c - EMB;                  // 0..95
    float val = 0.f;
    for (int ks = 0; ks < ksplit; ++ks)
      val += part[(size_t)ks * PART_STRIDE + (size_t)r * NCOLS + cc];
    res = val / cnt[cc >> 5];
  }
  out[(size_t)r * OUTC + c] = res;
}

// ---------------------------------------------------------------------------
extern "C" void kernel_launch(void* const* d_in, const int* in_sizes, int n_in,
                              void* d_out, int out_size, void* d_ws, size_t ws_size,
                              hipStream_t stream) {
  (void)in_sizes; (void)n_in; (void)out_size;
  const int*   x    = (const int*)d_in[0];
  const float* rate = (const float*)d_in[1];
  const float* wg   = (const float*)d_in[2];
  const float* wd   = (const float*)d_in[3];
  const float* wa   = (const float*)d_in[4];
  float* out  = (float*)d_out;
  float* part = (float*)d_ws;

  const size_t slab_bytes = PART_STRIDE * sizeof(float);   // 7.34 MB
  // Host-side KS choice from ws_size (host constant -> graph-capture safe).
  int KS;
  if      (ws_size >= 8 * slab_bytes + WFRAG_BYTES) KS = 8;
  else if (ws_size >= 4 * slab_bytes + WFRAG_BYTES) KS = 4;
  else if (ws_size >= 2 * slab_bytes + WFRAG_BYTES) KS = 2;
  else                                              KS = 1;
  uint4* Wfrag = (uint4*)((char*)d_ws + (size_t)KS * slab_bytes);

  prep_wfrag<<<KT_TOTAL, 256, 0, stream>>>(wg, wd, wa, Wfrag);
  switch (KS) {
    case 8: main_mm<8><<<8 * 256, 256, 0, stream>>>(x, Wfrag, part); break;
    case 4: main_mm<4><<<4 * 256, 256, 0, stream>>>(x, Wfrag, part); break;
    case 2: main_mm<2><<<2 * 256, 256, 0, stream>>>(x, Wfrag, part); break;
    default: main_mm<1><<<1 * 256, 256, 0, stream>>>(x, Wfrag, part); break;
  }
  reduce_k<<<B_ROWS, 128, 0, stream>>>(x, rate, part, KS, out);
}